// Round 2
// baseline (1061.726 us; speedup 1.0000x reference)
//
#include <hip/hip_runtime.h>
#include <hip/hip_bf16.h>
#include <hip/hip_fp16.h>

#define B 256
#define L 128
#define F 256
#define S 512
#define G4 1024  // 4*F gate rows

typedef _Float16 h2raw __attribute__((ext_vector_type(2)));

__device__ __forceinline__ float fdot2u(unsigned a, unsigned b, float c) {
#if __has_builtin(__builtin_amdgcn_fdot2)
    return __builtin_amdgcn_fdot2(__builtin_bit_cast(h2raw, a), __builtin_bit_cast(h2raw, b), c, false);
#else
    __half2 ah = __builtin_bit_cast(__half2, a), bh = __builtin_bit_cast(__half2, b);
    float2 af = __half22float2(ah), bf = __half22float2(bh);
    return c + af.x * bf.x + af.y * bf.y;
#endif
}

// wave-uniform broadcast of lane `lane`'s dword (compile-time lane index)
__device__ __forceinline__ unsigned bcast_lane(unsigned v, int lane) {
#if __has_builtin(__builtin_amdgcn_readlane)
    return (unsigned)__builtin_amdgcn_readlane((int)v, lane);
#else
    return (unsigned)__shfl((int)v, lane, 64);
#endif
}

__device__ __forceinline__ void sched_fence() {
#if __has_builtin(__builtin_amdgcn_sched_barrier)
    __builtin_amdgcn_sched_barrier(0);
#endif
}

// fast device transcendentals: v_exp_f32 / v_rcp_f32 based
__device__ __forceinline__ float fast_rcp(float x) { return __builtin_amdgcn_rcpf(x); }
__device__ __forceinline__ float sigf(float x) {
    float e = __expf(-x);
    return fast_rcp(1.0f + e);
}
__device__ __forceinline__ float tanhf_fast(float x) {
    x = fminf(fmaxf(x, -15.0f), 15.0f);
    float e = __expf(-2.0f * x);
    return (1.0f - e) * fast_rcp(1.0f + e);
}

// Prep: pack combined W = W_ih + W_hh for the 512-thread main kernel.
// Wave-level k-half mapping: j = tid&255 (hidden unit), q = tid>>8 (k-half).
// Chunk n in [0,64): n<48 -> register gates g=n>>4 (i,f,g), m=n&15;
//                    n>=48 -> LDS gate g=3 (o), m=n-48.
// Wpk[n*512+tid] = 4 half2 = k-pairs kp = q*64 + m*4 + {0..3} of row g*256+j.
__global__ void prep_kernel(const float* __restrict__ Wih,
                            const float* __restrict__ Whh,
                            const float* __restrict__ bih,
                            const float* __restrict__ bhh,
                            uint4* __restrict__ Wpk, float* __restrict__ bias_sum) {
    int e = blockIdx.x * blockDim.x + threadIdx.x;  // 32768 elements
    if (e < G4) bias_sum[e] = bih[e] + bhh[e];
    int n = e >> 9, tid = e & 511;
    int j = tid & 255, q = tid >> 8;   // wave-level k-half mapping
    int g = (n < 48) ? (n >> 4) : 3;
    int m = (n < 48) ? (n & 15) : (n - 48);
    int r = g * F + j;
    int kp0 = q * 64 + m * 4;
    unsigned pk[4];
    #pragma unroll
    for (int i = 0; i < 4; ++i) {
        int k = 2 * (kp0 + i);
        float w0 = Wih[(size_t)r * F + k]     + Whh[(size_t)r * F + k];
        float w1 = Wih[(size_t)r * F + k + 1] + Whh[(size_t)r * F + k + 1];
        pk[i] = __builtin_bit_cast(unsigned, __floats2half2_rn(w0, w1));
    }
    Wpk[(size_t)n * 512 + tid] = make_uint4(pk[0], pk[1], pk[2], pk[3]);
}

// init = elu(x[0] @ Wi.T + bi) -> h0, c0 (fp32 in workspace), float4 loads
__global__ void init_kernel(const float* __restrict__ x,
                            const float* __restrict__ Wi,
                            const float* __restrict__ bi,
                            float* __restrict__ h, float* __restrict__ c) {
    __shared__ float4 xs4[L / 4];
    int b = blockIdx.x, j = threadIdx.x;
    if (j < L / 4) xs4[j] = ((const float4*)(x + (size_t)b * L))[j];
    __syncthreads();
    float acc = bi[j];
    const float4* wp = (const float4*)(Wi + (size_t)j * L);
    #pragma unroll 8
    for (int k = 0; k < L / 4; ++k) {
        float4 w = wp[k], xv = xs4[k];
        acc += w.x * xv.x + w.y * xv.y + w.z * xv.z + w.w * xv.w;
    }
    float v = acc > 0.0f ? acc : expm1f(acc);
    h[b * F + j] = v;
    c[b * F + j] = v;
}

// Step 0: gates = last_feat @ W_ih.T + h0 @ W_hh.T + bias.
// 1024 threads: j = tid&255, q = tid>>8 picks a 128-wide slice of the
// concatenated K=512 ([inp;h0]) dimension. float4 loads, LDS partial reduce.
__global__ void step0_kernel(const float* __restrict__ lf,
                             const float* __restrict__ Wih,
                             const float* __restrict__ Whh,
                             const float* __restrict__ bias_sum,
                             float* __restrict__ h, float* __restrict__ c,
                             float* __restrict__ out) {
    __shared__ float vecs[2 * F];            // [inp(256) ; h0(256)]
    __shared__ float partial[3][4][F];
    int b = blockIdx.x, tid = threadIdx.x;
    int j = tid & (F - 1), q = tid >> 8;
    if (q == 0) vecs[j] = lf[(size_t)b * F + j];
    else if (q == 1) vecs[F + j] = h[(size_t)b * F + j];
    __syncthreads();
    const float* mat = (q < 2) ? Wih : Whh;
    int ks = (q & 1) * 128;
    const float4* vp = (const float4*)(&vecs[(q >> 1) * F + ks]);
    float a[4] = {0.f, 0.f, 0.f, 0.f};
    #pragma unroll
    for (int g = 0; g < 4; ++g) {
        const float4* wp = (const float4*)(&mat[(size_t)(g * F + j) * F + ks]);
        float acc = 0.f;
        #pragma unroll 8
        for (int i = 0; i < 32; ++i) {
            float4 w = wp[i], v = vp[i];
            acc += w.x * v.x + w.y * v.y + w.z * v.z + w.w * v.w;
        }
        a[g] = acc;
    }
    if (q > 0) {
        #pragma unroll
        for (int g = 0; g < 4; ++g) partial[q - 1][g][j] = a[g];
    }
    __syncthreads();
    if (q == 0) {
        #pragma unroll
        for (int g = 0; g < 4; ++g) {
            for (int p = 0; p < 3; ++p) a[g] += partial[p][g][j];
            a[g] += bias_sum[g * F + j];
        }
        float c0v = c[(size_t)b * F + j];
        float c1v = sigf(a[1]) * c0v + sigf(a[0]) * tanhf_fast(a[2]);
        float h1v = sigf(a[3]) * tanhf_fast(c1v);
        h[(size_t)b * F + j] = h1v;
        c[(size_t)b * F + j] = c1v;
        out[(size_t)b * F + j] = h1v;  // t=0 row
    }
}

// Main recurrence. One block of 512 threads per batch element.
// j = tid&255 (hidden unit), qw = tid>>8 (k-half, WAVE-level).
// h ingest: 1 ds_read_b32/wave + v_readlane wave-uniform broadcasts (no
// per-lane replicated LDS reads, no bank conflicts).
// v3 structural fixes vs v2 (which regressed 806->911 on serialization):
//  * DEFERRED out-store: step t's global store issues at the TOP of step
//    t+1, so the barrier's implicit s_waitcnt vmcnt(0) drain happens
//    ~1500 cy after issue (hidden) instead of immediately (serial ~300cy).
//  * SYMMETRIC reduction: both k-halves write pbuf[qw], read pbuf[qw^1],
//    and redundantly compute the nonlinearity. No idle half-block tail;
//    qw=1 writes hbuf while qw=0 owns the out store (parallel).
//  * Single-buffered pbuf/hbuf remain race-free:
//    pbuf: write < bar1 < read < bar2 < next write.
//    hbuf: read(top) < bar1 < write < bar2 < next read.
__launch_bounds__(512, 2)
__global__ void lstm_main(const uint4* __restrict__ Wpk,
                          const float* __restrict__ bias_sum,
                          const float* __restrict__ h_in,
                          const float* __restrict__ c_in,
                          float* __restrict__ out) {
    int b = blockIdx.x;
    int tid = threadIdx.x;
    int j = tid & (F - 1);
    int qw = tid >> 8;
    int lane = tid & 63;

    __shared__ uint4 lds_wo[16][512];   // gate-o weights, 128 KB
    __shared__ unsigned hbuf[F / 2];    // h as 128 packed half2 (single buffer)
    __shared__ float4 pbuf[2][F];       // symmetric partial gate sums, 8 KB

    // One-time: gates i,f,g into registers (coalesced), gate o into LDS.
    uint4 wr[48];
    #pragma unroll
    for (int n = 0; n < 48; ++n) wr[n] = Wpk[(size_t)n * 512 + tid];
    #pragma unroll
    for (int m = 0; m < 16; ++m) lds_wo[m][tid] = Wpk[(size_t)(48 + m) * 512 + tid];

    // bias folded into qw=0's accumulator init only (exactly once per gate sum)
    float bini0 = 0.f, bini1 = 0.f, bini2 = 0.f, bini3 = 0.f;
    if (qw == 0) {
        bini0 = bias_sum[0 * F + j];
        bini1 = bias_sum[1 * F + j];
        bini2 = bias_sum[2 * F + j];
        bini3 = bias_sum[3 * F + j];
    }
    float cj = c_in[(size_t)b * F + j];   // both halves track c (replicated)

    if (tid < F) ((__half*)hbuf)[tid] = __float2half(h_in[(size_t)b * F + tid]);
    __syncthreads();

    const int hoff = qw * 64 + lane;                     // fixed gather address
    uint4 woA0 = lds_wo[0][tid], woA1 = lds_wo[1][tid];  // steady-state prefetch

    float hprev = 0.f;  // deferred out-store value (qw==0 path)
    for (int t = 1; t < S; ++t) {
        unsigned hword = hbuf[hoff];   // whole k-half of h, distributed over lanes
        // deferred store of previous step's h row: drains at bar1, hidden
        // under this step's fdot2 phase instead of stalling a barrier.
        if (qw == 0 && t > 1) {
            __builtin_nontemporal_store(hprev, &out[((size_t)(t - 1) * B + b) * F + j]);
        }
        float a0 = bini0, a1 = bini1, a2 = bini2, a3 = bini3;
        #pragma unroll
        for (int cc = 0; cc < 8; ++cc) {
            uint4 woB0, woB1;
            if (cc < 7) { woB0 = lds_wo[2 * cc + 2][tid]; woB1 = lds_wo[2 * cc + 3][tid]; }
            else        { woB0 = lds_wo[0][tid];          woB1 = lds_wo[1][tid]; }  // next step's
            #pragma unroll
            for (int u = 0; u < 2; ++u) {
                const int m = 2 * cc + u;
                uint4 wiv = wr[m];
                uint4 wfv = wr[16 + m];
                uint4 wgv = wr[32 + m];
                uint4 wov = (u == 0) ? woA0 : woA1;
                const unsigned* wip = (const unsigned*)&wiv;
                const unsigned* wfp = (const unsigned*)&wfv;
                const unsigned* wgp = (const unsigned*)&wgv;
                const unsigned* wop = (const unsigned*)&wov;
                #pragma unroll
                for (int e = 0; e < 4; ++e) {
                    unsigned hp = bcast_lane(hword, 4 * m + e);  // wave-uniform h pair
                    a0 = fdot2u(wip[e], hp, a0);
                    a1 = fdot2u(wfp[e], hp, a1);
                    a2 = fdot2u(wgp[e], hp, a2);
                    a3 = fdot2u(wop[e], hp, a3);
                }
            }
            woA0 = woB0; woA1 = woB1;
            sched_fence();  // keep chunk c+1's loads from hoisting further up
        }

        // symmetric cross-wave k-half reduction: everyone writes own partial,
        // reads partner's, and computes the tail redundantly.
        pbuf[qw][j] = make_float4(a0, a1, a2, a3);
        __syncthreads();   // bar1 (also drains the deferred out-store, cheap)
        float4 pp = pbuf[qw ^ 1][j];
        a0 += pp.x; a1 += pp.y; a2 += pp.z; a3 += pp.w;
        float c2 = sigf(a1) * cj + sigf(a0) * tanhf_fast(a2);
        float h2 = sigf(a3) * tanhf_fast(c2);
        cj = c2;
        if (qw == 1) ((__half*)hbuf)[j] = __float2half(h2);  // h feedback
        hprev = h2;
        __syncthreads();   // bar2: publishes hbuf for next step's gather
    }
    if (qw == 0) {
        __builtin_nontemporal_store(hprev, &out[((size_t)(S - 1) * B + b) * F + j]);
    }
}

extern "C" void kernel_launch(void* const* d_in, const int* in_sizes, int n_in,
                              void* d_out, int out_size, void* d_ws, size_t ws_size,
                              hipStream_t stream) {
    const float* x   = (const float*)d_in[0];
    const float* lf  = (const float*)d_in[1];
    const float* Wi  = (const float*)d_in[2];
    const float* bi  = (const float*)d_in[3];
    const float* Wih = (const float*)d_in[4];
    const float* Whh = (const float*)d_in[5];
    const float* bih = (const float*)d_in[6];
    const float* bhh = (const float*)d_in[7];
    // d_in[8], d_in[9] (Wo, bo): computed-and-discarded in the reference; unused.
    float* out = (float*)d_out;

    float* ws    = (float*)d_ws;
    float* h     = ws;               // 65536 floats
    float* c     = ws + 65536;       // 65536 floats
    float* bias  = ws + 131072;      // 1024 floats
    uint4* Wpk   = (uint4*)(ws + 132096);  // 64*512 x 16B = 512 KB

    prep_kernel<<<128, 256, 0, stream>>>(Wih, Whh, bih, bhh, Wpk, bias);
    init_kernel<<<B, F, 0, stream>>>(x, Wi, bi, h, c);
    step0_kernel<<<B, 1024, 0, stream>>>(lf, Wih, Whh, bias, h, c, out);
    lstm_main<<<B, 512, 0, stream>>>(Wpk, bias, h, c, out);
}

// Round 3
// 874.648 us; speedup vs baseline: 1.2139x; 1.2139x over previous
//
#include <hip/hip_runtime.h>
#include <hip/hip_bf16.h>
#include <hip/hip_fp16.h>

#define B 256
#define L 128
#define F 256
#define S 512
#define G4 1024  // 4*F gate rows

typedef _Float16 h2raw __attribute__((ext_vector_type(2)));

__device__ __forceinline__ float fdot2u(unsigned a, unsigned b, float c) {
#if __has_builtin(__builtin_amdgcn_fdot2)
    return __builtin_amdgcn_fdot2(__builtin_bit_cast(h2raw, a), __builtin_bit_cast(h2raw, b), c, false);
#else
    __half2 ah = __builtin_bit_cast(__half2, a), bh = __builtin_bit_cast(__half2, b);
    float2 af = __half22float2(ah), bf = __half22float2(bh);
    return c + af.x * bf.x + af.y * bf.y;
#endif
}

__device__ __forceinline__ void sched_fence() {
#if __has_builtin(__builtin_amdgcn_sched_barrier)
    __builtin_amdgcn_sched_barrier(0);
#endif
}

// fast device transcendentals: v_exp_f32 / v_rcp_f32 based
__device__ __forceinline__ float fast_rcp(float x) { return __builtin_amdgcn_rcpf(x); }
__device__ __forceinline__ float sigf(float x) {
    float e = __expf(-x);
    return fast_rcp(1.0f + e);
}
__device__ __forceinline__ float tanhf_fast(float x) {
    x = fminf(fmaxf(x, -15.0f), 15.0f);
    float e = __expf(-2.0f * x);
    return (1.0f - e) * fast_rcp(1.0f + e);
}

template <int CTRL>
__device__ __forceinline__ float dpp_add(float x) {
    int v = __builtin_amdgcn_update_dpp(0, __builtin_bit_cast(int, x), CTRL, 0xF, 0xF, true);
    return x + __builtin_bit_cast(float, v);
}

// Prep: pack combined W = W_ih + W_hh for the 512-thread main kernel.
// ROUND-0 thread mapping: tid: j = tid>>1 (hidden unit), q = tid&1 (k-half).
// Chunk n in [0,64): n<48 -> register gates g=n>>4 (i,f,g), m=n&15;
//                    n>=48 -> LDS gate g=3 (o), m=n-48.
// Wpk[n*512+tid] = 4 half2 = k-pairs kp = q*64 + m*4 + {0..3} of row g*256+j.
__global__ void prep_kernel(const float* __restrict__ Wih,
                            const float* __restrict__ Whh,
                            const float* __restrict__ bih,
                            const float* __restrict__ bhh,
                            uint4* __restrict__ Wpk, float* __restrict__ bias_sum) {
    int e = blockIdx.x * blockDim.x + threadIdx.x;  // 32768 elements
    if (e < G4) bias_sum[e] = bih[e] + bhh[e];
    int n = e >> 9, tid = e & 511;
    int j = tid >> 1, q = tid & 1;
    int g = (n < 48) ? (n >> 4) : 3;
    int m = (n < 48) ? (n & 15) : (n - 48);
    int r = g * F + j;
    int kp0 = q * 64 + m * 4;
    unsigned pk[4];
    #pragma unroll
    for (int i = 0; i < 4; ++i) {
        int k = 2 * (kp0 + i);
        float w0 = Wih[(size_t)r * F + k]     + Whh[(size_t)r * F + k];
        float w1 = Wih[(size_t)r * F + k + 1] + Whh[(size_t)r * F + k + 1];
        pk[i] = __builtin_bit_cast(unsigned, __floats2half2_rn(w0, w1));
    }
    Wpk[(size_t)n * 512 + tid] = make_uint4(pk[0], pk[1], pk[2], pk[3]);
}

// init = elu(x[0] @ Wi.T + bi) -> h0, c0 (fp32 in workspace), float4 loads
__global__ void init_kernel(const float* __restrict__ x,
                            const float* __restrict__ Wi,
                            const float* __restrict__ bi,
                            float* __restrict__ h, float* __restrict__ c) {
    __shared__ float4 xs4[L / 4];
    int b = blockIdx.x, j = threadIdx.x;
    if (j < L / 4) xs4[j] = ((const float4*)(x + (size_t)b * L))[j];
    __syncthreads();
    float acc = bi[j];
    const float4* wp = (const float4*)(Wi + (size_t)j * L);
    #pragma unroll 8
    for (int k = 0; k < L / 4; ++k) {
        float4 w = wp[k], xv = xs4[k];
        acc += w.x * xv.x + w.y * xv.y + w.z * xv.z + w.w * xv.w;
    }
    float v = acc > 0.0f ? acc : expm1f(acc);
    h[b * F + j] = v;
    c[b * F + j] = v;
}

// Step 0: gates = last_feat @ W_ih.T + h0 @ W_hh.T + bias.
// 1024 threads: j = tid&255, q = tid>>8 picks a 128-wide slice of the
// concatenated K=512 ([inp;h0]) dimension. float4 loads, LDS partial reduce.
__global__ void step0_kernel(const float* __restrict__ lf,
                             const float* __restrict__ Wih,
                             const float* __restrict__ Whh,
                             const float* __restrict__ bias_sum,
                             float* __restrict__ h, float* __restrict__ c,
                             float* __restrict__ out) {
    __shared__ float vecs[2 * F];            // [inp(256) ; h0(256)]
    __shared__ float partial[3][4][F];
    int b = blockIdx.x, tid = threadIdx.x;
    int j = tid & (F - 1), q = tid >> 8;
    if (q == 0) vecs[j] = lf[(size_t)b * F + j];
    else if (q == 1) vecs[F + j] = h[(size_t)b * F + j];
    __syncthreads();
    const float* mat = (q < 2) ? Wih : Whh;
    int ks = (q & 1) * 128;
    const float4* vp = (const float4*)(&vecs[(q >> 1) * F + ks]);
    float a[4] = {0.f, 0.f, 0.f, 0.f};
    #pragma unroll
    for (int g = 0; g < 4; ++g) {
        const float4* wp = (const float4*)(&mat[(size_t)(g * F + j) * F + ks]);
        float acc = 0.f;
        #pragma unroll 8
        for (int i = 0; i < 32; ++i) {
            float4 w = wp[i], v = vp[i];
            acc += w.x * v.x + w.y * v.y + w.z * v.z + w.w * v.w;
        }
        a[g] = acc;
    }
    if (q > 0) {
        #pragma unroll
        for (int g = 0; g < 4; ++g) partial[q - 1][g][j] = a[g];
    }
    __syncthreads();
    if (q == 0) {
        #pragma unroll
        for (int g = 0; g < 4; ++g) {
            for (int p = 0; p < 3; ++p) a[g] += partial[p][g][j];
            a[g] += bias_sum[g * F + j];
        }
        float c0v = c[(size_t)b * F + j];
        float c1v = sigf(a[1]) * c0v + sigf(a[0]) * tanhf_fast(a[2]);
        float h1v = sigf(a[3]) * tanhf_fast(c1v);
        h[(size_t)b * F + j] = h1v;
        c[(size_t)b * F + j] = c1v;
        out[(size_t)b * F + j] = h1v;  // t=0 row
    }
}

// Main recurrence. One block of 512 threads per batch element.
// j = tid>>1 (hidden unit), q = tid&1 (k-half, reduced via DPP xor-1).
// Weights: gates i,f,g register-resident (192 dwords/thread); gate o in LDS.
// K-loop runs in 8 chunks of 2 with 1-chunk prefetch + sched fences so peak
// liveness stays ~243 <= 256 regs -> no AGPR shuttle.
// v4 vs round-0 (806us): two isolated fixes, structure otherwise identical.
//  * hbuf BANK-PAD: q=1 half shifted +16B (17-uint4 stride). Round-0's hv
//    broadcast reads were 2-address (q=0 at X, q=1 at X+256B) where
//    256B = 0 mod 128B -> both groups hit the SAME banks = the measured
//    512 conflict cy/step. With the pad, q=0 uses banks 4i..4i+3 and
//    q=1 uses 4i+4..4i+7 -> disjoint.
//  * DEFERRED out-store: step t's global store issues at the TOP of step
//    t+1 so the s_waitcnt vmcnt(0) before s_barrier drains a ~3000cy-old
//    store (free) instead of a fresh one (~300cy serial).
__launch_bounds__(512, 2)
__global__ void lstm_main(const uint4* __restrict__ Wpk,
                          const float* __restrict__ bias_sum,
                          const float* __restrict__ h_in,
                          const float* __restrict__ c_in,
                          float* __restrict__ out) {
    int b = blockIdx.x;
    int tid = threadIdx.x;
    int j = tid >> 1;
    int q = tid & 1;

    __shared__ uint4 lds_wo[16][512];   // gate-o weights, 128 KB
    __shared__ uint4 hbuf4[2][34];      // 2 buffers x (2 halves x 17 uint4, 16B pad)

    // One-time: gates i,f,g into registers (coalesced), gate o into LDS.
    uint4 wr[48];
    #pragma unroll
    for (int n = 0; n < 48; ++n) wr[n] = Wpk[(size_t)n * 512 + tid];
    #pragma unroll
    for (int m = 0; m < 16; ++m) lds_wo[m][tid] = Wpk[(size_t)(48 + m) * 512 + tid];

    float bias0 = bias_sum[0 * F + j];
    float bias1 = bias_sum[1 * F + j];
    float bias2 = bias_sum[2 * F + j];
    float bias3 = bias_sum[3 * F + j];
    float cj = c_in[(size_t)b * F + j];

    // initial h fill: k-element tid -> half index (tid>>7)*17 uint4 half-buffer,
    // within-half half-index tid&127
    if (tid < F) {
        __half* hp = (__half*)&hbuf4[0][(tid >> 7) * 17];
        hp[tid & 127] = __float2half(h_in[(size_t)b * F + tid]);
    }
    __syncthreads();

    int cur = 0;
    float hprev = 0.f;  // deferred out-store value (q==1 path)
    for (int t = 1; t < S; ++t) {
        const uint4* hb = &hbuf4[cur][q * 17];
        // deferred store of previous step's h row (odd lanes): issued here,
        // drained by the end-of-step barrier ~3000cy later -> hidden.
        if (q == 1 && t > 1) {
            __builtin_nontemporal_store(hprev, &out[((size_t)(t - 1) * B + b) * F + j]);
        }
        float a0 = 0.f, a1 = 0.f, a2 = 0.f, a3 = 0.f;

        uint4 hvA0 = hb[0], hvA1 = hb[1];
        uint4 woA0 = lds_wo[0][tid], woA1 = lds_wo[1][tid];
        #pragma unroll
        for (int c = 0; c < 8; ++c) {
            uint4 hvB0, hvB1, woB0, woB1;
            if (c < 7) {
                hvB0 = hb[2 * c + 2];
                hvB1 = hb[2 * c + 3];
                woB0 = lds_wo[2 * c + 2][tid];
                woB1 = lds_wo[2 * c + 3][tid];
            }
            #pragma unroll
            for (int u = 0; u < 2; ++u) {
                const int i = 2 * c + u;
                uint4 hv = (u == 0) ? hvA0 : hvA1;
                uint4 w3 = (u == 0) ? woA0 : woA1;
                uint4 w0 = wr[i];
                uint4 w1 = wr[16 + i];
                uint4 w2 = wr[32 + i];
                a0 = fdot2u(w0.x, hv.x, a0); a0 = fdot2u(w0.y, hv.y, a0);
                a0 = fdot2u(w0.z, hv.z, a0); a0 = fdot2u(w0.w, hv.w, a0);
                a1 = fdot2u(w1.x, hv.x, a1); a1 = fdot2u(w1.y, hv.y, a1);
                a1 = fdot2u(w1.z, hv.z, a1); a1 = fdot2u(w1.w, hv.w, a1);
                a2 = fdot2u(w2.x, hv.x, a2); a2 = fdot2u(w2.y, hv.y, a2);
                a2 = fdot2u(w2.z, hv.z, a2); a2 = fdot2u(w2.w, hv.w, a2);
                a3 = fdot2u(w3.x, hv.x, a3); a3 = fdot2u(w3.y, hv.y, a3);
                a3 = fdot2u(w3.z, hv.z, a3); a3 = fdot2u(w3.w, hv.w, a3);
            }
            hvA0 = hvB0; hvA1 = hvB1; woA0 = woB0; woA1 = woB1;
            sched_fence();  // keep chunk c+1's loads from hoisting further up
        }

        // sum the 2 k-halves (lane pairs); both lanes get full sums
        a0 = dpp_add<0xB1>(a0) + bias0;
        a1 = dpp_add<0xB1>(a1) + bias1;
        a2 = dpp_add<0xB1>(a2) + bias2;
        a3 = dpp_add<0xB1>(a3) + bias3;
        float c2 = sigf(a1) * cj + sigf(a0) * tanhf_fast(a2);
        float h2 = sigf(a3) * tanhf_fast(c2);
        cj = c2;
        if (q == 0) {
            __half* hp = (__half*)&hbuf4[cur ^ 1][(j >> 7) * 17];
            hp[j & 127] = __float2half(h2);
        }
        hprev = h2;
        __syncthreads();
        cur ^= 1;
    }
    if (q == 1) {
        __builtin_nontemporal_store(hprev, &out[((size_t)(S - 1) * B + b) * F + j]);
    }
}

extern "C" void kernel_launch(void* const* d_in, const int* in_sizes, int n_in,
                              void* d_out, int out_size, void* d_ws, size_t ws_size,
                              hipStream_t stream) {
    const float* x   = (const float*)d_in[0];
    const float* lf  = (const float*)d_in[1];
    const float* Wi  = (const float*)d_in[2];
    const float* bi  = (const float*)d_in[3];
    const float* Wih = (const float*)d_in[4];
    const float* Whh = (const float*)d_in[5];
    const float* bih = (const float*)d_in[6];
    const float* bhh = (const float*)d_in[7];
    // d_in[8], d_in[9] (Wo, bo): computed-and-discarded in the reference; unused.
    float* out = (float*)d_out;

    float* ws    = (float*)d_ws;
    float* h     = ws;               // 65536 floats
    float* c     = ws + 65536;       // 65536 floats
    float* bias  = ws + 131072;      // 1024 floats
    uint4* Wpk   = (uint4*)(ws + 132096);  // 64*512 x 16B = 512 KB

    prep_kernel<<<128, 256, 0, stream>>>(Wih, Whh, bih, bhh, Wpk, bias);
    init_kernel<<<B, F, 0, stream>>>(x, Wi, bi, h, c);
    step0_kernel<<<B, 1024, 0, stream>>>(lf, Wih, Whh, bias, h, c, out);
    lstm_main<<<B, 512, 0, stream>>>(Wpk, bias, h, c, out);
}